// Round 3
// baseline (641.245 us; speedup 1.0000x reference)
//
#include <hip/hip_runtime.h>

#define BT 32
#define CH 64
#define HS 56
#define WS 56
#define HH 28
#define WH 28

// ---------------- filter constants (exact reference values) ----------------
namespace {
constexpr float ISQ2 = 0.70710678118654752440f;
constexpr float F_H0[13] = {-0.0017578125f, 0.0f, 0.022265625f, -0.046875f,
    -0.0482421875f, 0.296875f, 0.55546875f, 0.296875f, -0.0482421875f,
    -0.046875f, 0.022265625f, 0.0f, -0.0017578125f};
constexpr float F_H1[19] = {-7.0626e-05f, 0.0f, 0.00134189f, -0.00188341f,
    -0.0071566f, 0.023856f, 0.0556431f, -0.0516881f, -0.299758f, 0.559431f,
    -0.299758f, -0.0516881f, 0.0556431f, 0.023856f, -0.0071566f,
    -0.00188341f, 0.00134189f, 0.0f, -7.0626e-05f};
constexpr float F_G0[19] = {7.0626e-05f, 0.0f, -0.00134189f, -0.00188341f,
    0.0071566f, 0.023856f, -0.0556431f, -0.0516881f, 0.299758f, 0.559431f,
    0.299758f, -0.0516881f, -0.0556431f, 0.023856f, 0.0071566f,
    -0.00188341f, -0.00134189f, 0.0f, 7.0626e-05f};
constexpr float F_G1[13] = {-0.0017578125f, 0.0f, 0.022265625f, 0.046875f,
    -0.0482421875f, -0.296875f, 0.55546875f, -0.296875f, -0.0482421875f,
    0.046875f, 0.022265625f, 0.0f, -0.0017578125f};
}

__device__ __forceinline__ int symi(int k) {
    k = (k < 0) ? (-1 - k) : k;
    k = (k >= HS) ? (2 * HS - 1 - k) : k;
    return k;
}

// ---- K0: transpose w_ll [c][h][w] -> wllT [h][w][c] (staged in d_out head)
__global__ __launch_bounds__(256) void k_wll_T(const float* __restrict__ wll,
                                               float* __restrict__ wllT) {
    __shared__ float tile[64][65];
    int pos0 = blockIdx.x * 64;
    int lp = threadIdx.x & 63, g = threadIdx.x >> 6;
#pragma unroll
    for (int r = 0; r < 16; ++r) {
        int cc = r * 4 + g;
        tile[cc][lp] = wll[cc * (HS * WS) + pos0 + lp];
    }
    __syncthreads();
#pragma unroll
    for (int r = 0; r < 16; ++r) {
        int pl = r * 4 + g;
        wllT[(pos0 + pl) * CH + lp] = tile[lp][pl];
    }
}

// ---- K1: forward row filters (sliding window, no LDS): x -> lo, hi
__global__ __launch_bounds__(256, 2) void k_fwd_rows(const float* __restrict__ x,
                                                     float* __restrict__ lo,
                                                     float* __restrict__ hi) {
    int b = blockIdx.x / HS, h = blockIdx.x % HS;
    int strip = threadIdx.x >> 6, c = threadIdx.x & 63;
    int base = (b * HS + h) * WS * CH + c;
    const float* row = x + base;
    float* lop = lo + base;
    float* hip = hi + base;
    int w0s = strip * 14;
    float W[19];
#pragma unroll
    for (int t = 0; t < 19; ++t) W[t] = row[symi(w0s - 9 + t) * CH];
#pragma unroll 7
    for (int k = 0; k < 14; ++k) {
        int w = w0s + k;
        float aLo = 0.f, aHi = 0.f;
#pragma unroll
        for (int t = 0; t < 13; ++t) aLo += F_H0[t] * W[3 + t];
#pragma unroll
        for (int t = 0; t < 19; ++t) aHi += F_H1[t] * W[t];
        lop[w * CH] = aLo;
        hip[w * CH] = aHi;
#pragma unroll
        for (int t = 0; t < 18; ++t) W[t] = W[t + 1];
        W[18] = row[symi(w + 10) * CH];
    }
}

// ---- K2a: lo path: sliding-window column filters + batched q2c + mixing
// yh layout: [b][s][i][wp][ri][c]
__global__ __launch_bounds__(256, 2) void k_lo_mix(
    const float* __restrict__ lo, const float* __restrict__ wllT,
    const float* __restrict__ w1, const float* __restrict__ w2,
    const float* __restrict__ b1, const float* __restrict__ b2,
    float* __restrict__ xl, float* __restrict__ yh) {
    __shared__ float sw1[2][16][4][16];   // [ri][d][nb][k] 8 KB
    __shared__ float sw2[2][16][4][16];   // 8 KB
    __shared__ float sbias[2][2][4][16];  // [layer][ri][nb][k] 1 KB
    __shared__ float qT[4][64][29];       // [j][c][i pad29] 29.7 KB

    int b = blockIdx.x / WH, wp = blockIdx.x % WH;
    int w0 = 2 * wp, tid = threadIdx.x;

    for (int idx = tid; idx < 2048; idx += 256) {
        int ri = idx >> 10, rem = idx & 1023;
        int nb = rem >> 8, dd = (rem >> 4) & 15, k = idx & 15;
        sw1[ri][dd][nb][k] = w1[idx];
        sw2[ri][dd][nb][k] = w2[idx];
    }
    if (tid < 128) {
        (&sbias[0][0][0][0])[tid] = b1[tid];
        (&sbias[1][0][0][0])[tid] = b2[tid];
    }

    int q = tid >> 6, c = tid & 63;
    int rp = q >> 1, jc = q & 1;
    const float* colbase = lo + (b * HS) * WS * CH + (w0 + jc) * CH + c;
    {
        float W[19];
#pragma unroll
        for (int t = 0; t < 19; ++t) W[t] = colbase[symi(rp - 9 + t) * (WS * CH)];
#pragma unroll 7
        for (int i = 0; i < 28; ++i) {
            int h = 2 * i + rp;
            float vll = 0.f, vlh = 0.f;
#pragma unroll
            for (int t = 0; t < 13; ++t) vll += F_H0[t] * W[3 + t];
#pragma unroll
            for (int t = 0; t < 19; ++t) vlh += F_H1[t] * W[t];
            xl[((b * HS + h) * WS + (w0 + jc)) * CH + c] =
                vll * wllT[(h * WS + (w0 + jc)) * CH + c];
            qT[q][c][i] = vlh;
#pragma unroll
            for (int t = 0; t < 17; ++t) W[t] = W[t + 2];
            W[17] = colbase[symi(h + 10) * (WS * CH)];
            W[18] = colbase[symi(h + 11) * (WS * CH)];
        }
    }
    __syncthreads();

    // in-place butterfly (q2c)
    {
        int cc = tid & 63, g = tid >> 6;
#pragma unroll
        for (int r = 0; r < 7; ++r) {
            int i = g * 7 + r;
            float a = qT[0][cc][i], bb = qT[1][cc][i];
            float cv = qT[2][cc][i], dv = qT[3][cc][i];
            qT[0][cc][i] = (a - dv) * ISQ2;
            qT[1][cc][i] = (bb + cv) * ISQ2;
            qT[2][cc][i] = (a + dv) * ISQ2;
            qT[3][cc][i] = (bb - cv) * ISQ2;
        }
    }
    __syncthreads();

    // mix: item = (kh 2, nb 4, i 28, p 2) = 448 items; layer1 duplicated per kh
#pragma unroll 1
    for (int it = tid; it < 448; it += 256) {
        int kh = it & 1;
        int nb = (it >> 1) & 3;
        int r = it >> 3;  // 0..55
        int i = r % 28, p = r / 28;
        float l1r[16], l1i[16];
#pragma unroll
        for (int k = 0; k < 16; ++k) { l1r[k] = sbias[0][0][nb][k]; l1i[k] = sbias[0][1][nb][k]; }
#pragma unroll
        for (int d = 0; d < 16; ++d) {
            float xr = qT[2 * p][nb * 16 + d][i], xi = qT[2 * p + 1][nb * 16 + d][i];
#pragma unroll
            for (int k = 0; k < 16; ++k) {
                float wr = sw1[0][d][nb][k], wi = sw1[1][d][nb][k];
                l1r[k] += xr * wr - xi * wi;
                l1i[k] += xr * wi + xi * wr;
            }
        }
#pragma unroll
        for (int k = 0; k < 16; ++k) { l1r[k] = fmaxf(l1r[k], 0.f); l1i[k] = fmaxf(l1i[k], 0.f); }
        float orr[8], oii[8];
#pragma unroll
        for (int k = 0; k < 8; ++k) { orr[k] = sbias[1][0][nb][kh * 8 + k]; oii[k] = sbias[1][1][nb][kh * 8 + k]; }
#pragma unroll
        for (int d = 0; d < 16; ++d) {
            float xr = l1r[d], xi = l1i[d];
#pragma unroll
            for (int k = 0; k < 8; ++k) {
                float wr = sw2[0][d][nb][kh * 8 + k], wi = sw2[1][d][nb][kh * 8 + k];
                orr[k] += xr * wr - xi * wi;
                oii[k] += xr * wi + xi * wr;
            }
        }
        int s = p ? 5 : 0;
        int o = ((((b * 6 + s) * HH + i) * WH + wp) * 2) * CH + nb * 16 + kh * 8;
        *(float4*)(yh + o) = make_float4(orr[0], orr[1], orr[2], orr[3]);
        *(float4*)(yh + o + 4) = make_float4(orr[4], orr[5], orr[6], orr[7]);
        *(float4*)(yh + o + CH) = make_float4(oii[0], oii[1], oii[2], oii[3]);
        *(float4*)(yh + o + CH + 4) = make_float4(oii[4], oii[5], oii[6], oii[7]);
    }
}

// ---- K2b: hi path: same structure, 4 subbands, two half-rounds of i
__global__ __launch_bounds__(256, 2) void k_hi_mix(
    const float* __restrict__ hi, const float* __restrict__ w1,
    const float* __restrict__ w2, const float* __restrict__ b1,
    const float* __restrict__ b2, float* __restrict__ yh) {
    __shared__ float sw1[2][16][4][16];
    __shared__ float sw2[2][16][4][16];
    __shared__ float sbias[2][2][4][16];
    __shared__ float qT[2][4][64][15];  // [src 0=hl 1=hh][j][c][ii pad15] 30.7 KB

    int b = blockIdx.x / WH, wp = blockIdx.x % WH;
    int w0 = 2 * wp, tid = threadIdx.x;

    for (int idx = tid; idx < 2048; idx += 256) {
        int ri = idx >> 10, rem = idx & 1023;
        int nb = rem >> 8, dd = (rem >> 4) & 15, k = idx & 15;
        sw1[ri][dd][nb][k] = w1[idx];
        sw2[ri][dd][nb][k] = w2[idx];
    }
    if (tid < 128) {
        (&sbias[0][0][0][0])[tid] = b1[tid];
        (&sbias[1][0][0][0])[tid] = b2[tid];
    }

    int q = tid >> 6, c = tid & 63;
    int rp = q >> 1, jc = q & 1;
    const float* colbase = hi + (b * HS) * WS * CH + (w0 + jc) * CH + c;

    for (int half = 0; half < 2; ++half) {
        {
            int h0 = 28 * half + rp;
            float W[19];  // re-initialized each half so it is dead across the mix
#pragma unroll
            for (int t = 0; t < 19; ++t) W[t] = colbase[symi(h0 - 9 + t) * (WS * CH)];
#pragma unroll 7
            for (int ii = 0; ii < 14; ++ii) {
                int h = h0 + 2 * ii;
                float vhl = 0.f, vhh = 0.f;
#pragma unroll
                for (int t = 0; t < 13; ++t) vhl += F_H0[t] * W[3 + t];
#pragma unroll
                for (int t = 0; t < 19; ++t) vhh += F_H1[t] * W[t];
                qT[0][q][c][ii] = vhl;
                qT[1][q][c][ii] = vhh;
#pragma unroll
                for (int t = 0; t < 17; ++t) W[t] = W[t + 2];
                W[17] = colbase[symi(h + 10) * (WS * CH)];
                W[18] = colbase[symi(h + 11) * (WS * CH)];
            }
        }
        __syncthreads();
        {
            int cc = tid & 63, g = tid >> 6;
#pragma unroll
            for (int r = 0; r < 7; ++r) {
                int slice = g * 7 + r;
                int src = slice / 14, ii = slice % 14;
                float a = qT[src][0][cc][ii], bb = qT[src][1][cc][ii];
                float cv = qT[src][2][cc][ii], dv = qT[src][3][cc][ii];
                qT[src][0][cc][ii] = (a - dv) * ISQ2;
                qT[src][1][cc][ii] = (bb + cv) * ISQ2;
                qT[src][2][cc][ii] = (a + dv) * ISQ2;
                qT[src][3][cc][ii] = (bb - cv) * ISQ2;
            }
        }
        __syncthreads();
        // mix: item = (kh 2, nb 4, ii 14, sq 4) = 448 items
#pragma unroll 1
        for (int it = tid; it < 448; it += 256) {
            int kh = it & 1;
            int nb = (it >> 1) & 3;
            int r = it >> 3;  // 0..55
            int ii = r % 14, sq = r / 14;            // s = sq+1
            int src = (sq == 0 || sq == 3) ? 1 : 0;  // s1,s4 from hh
            int sec = (sq >= 2) ? 1 : 0;             // s3,s4 are "second"
            float l1r[16], l1i[16];
#pragma unroll
            for (int k = 0; k < 16; ++k) { l1r[k] = sbias[0][0][nb][k]; l1i[k] = sbias[0][1][nb][k]; }
#pragma unroll
            for (int d = 0; d < 16; ++d) {
                float xr = qT[src][2 * sec][nb * 16 + d][ii];
                float xi = qT[src][2 * sec + 1][nb * 16 + d][ii];
#pragma unroll
                for (int k = 0; k < 16; ++k) {
                    float wr = sw1[0][d][nb][k], wi = sw1[1][d][nb][k];
                    l1r[k] += xr * wr - xi * wi;
                    l1i[k] += xr * wi + xi * wr;
                }
            }
#pragma unroll
            for (int k = 0; k < 16; ++k) { l1r[k] = fmaxf(l1r[k], 0.f); l1i[k] = fmaxf(l1i[k], 0.f); }
            float orr[8], oii[8];
#pragma unroll
            for (int k = 0; k < 8; ++k) { orr[k] = sbias[1][0][nb][kh * 8 + k]; oii[k] = sbias[1][1][nb][kh * 8 + k]; }
#pragma unroll
            for (int d = 0; d < 16; ++d) {
                float xr = l1r[d], xi = l1i[d];
#pragma unroll
                for (int k = 0; k < 8; ++k) {
                    float wr = sw2[0][d][nb][kh * 8 + k], wi = sw2[1][d][nb][kh * 8 + k];
                    orr[k] += xr * wr - xi * wi;
                    oii[k] += xr * wi + xi * wr;
                }
            }
            int i = half * 14 + ii, s = sq + 1;
            int o = ((((b * 6 + s) * HH + i) * WH + wp) * 2) * CH + nb * 16 + kh * 8;
            *(float4*)(yh + o) = make_float4(orr[0], orr[1], orr[2], orr[3]);
            *(float4*)(yh + o + 4) = make_float4(orr[4], orr[5], orr[6], orr[7]);
            *(float4*)(yh + o + CH) = make_float4(oii[0], oii[1], oii[2], oii[3]);
            *(float4*)(yh + o + CH + 4) = make_float4(oii[4], oii[5], oii[6], oii[7]);
        }
        __syncthreads();
    }
}

// ---- K3: inverse column filters (sliding window, no LDS, c2q on the fly)
// mode 0: lo2 = G0*xl + G1*c2q(s0,s5);  mode 1: hi2 = G0*c2q(s2,s3) + G1*c2q(s1,s4)
__global__ __launch_bounds__(256, 2) void k_inv_cols(const float* __restrict__ xl,
                                                     const float* __restrict__ yh,
                                                     float* __restrict__ lo2,
                                                     float* __restrict__ hi2) {
    int mode = blockIdx.y;
    int b = blockIdx.x / 14, wg = blockIdx.x % 14;
    int wl = threadIdx.x >> 6, c = threadIdx.x & 63;
    int w = wg * 4 + wl, wp = w >> 1, jw = w & 1;
    const int stepi = WH * 2 * CH;  // 3584
    int cbase = wp * 2 * CH + c;

    int baseA1 = 0, baseA2 = 0, baseB1, baseB2;
    if (mode == 0) {
        baseB1 = ((b * 6 + 0) * HH) * stepi + cbase;
        baseB2 = ((b * 6 + 5) * HH) * stepi + cbase;
    } else {
        baseA1 = ((b * 6 + 2) * HH) * stepi + cbase;
        baseA2 = ((b * 6 + 3) * HH) * stepi + cbase;
        baseB1 = ((b * 6 + 1) * HH) * stepi + cbase;
        baseB2 = ((b * 6 + 4) * HH) * stepi + cbase;
    }
    int xbase = (b * HS) * WS * CH + w * CH + c;

    auto c2q = [&](int b1_, int b2_, int r) -> float {
        int i = r >> 1, sel = (r & 1) ^ jw;
        float u = yh[b1_ + i * stepi + sel * CH];
        float v = yh[b2_ + i * stepi + sel * CH];
        float val = ((r & 1) == 0) ? (u + v) : ((jw == 0) ? (u - v) : (v - u));
        return val * ISQ2;
    };
    auto ldA = [&](int r) -> float {
        if (mode == 0) return xl[xbase + r * (WS * CH)];
        return c2q(baseA1, baseA2, r);
    };
    auto ldB = [&](int r) -> float { return c2q(baseB1, baseB2, r); };
    float* outp = mode ? hi2 : lo2;

    float A[19], B[13];
#pragma unroll
    for (int t = 0; t < 19; ++t) A[t] = ldA(symi(t - 9));
#pragma unroll
    for (int t = 0; t < 13; ++t) B[t] = ldB(symi(t - 6));
#pragma unroll 4
    for (int h = 0; h < 56; ++h) {
        float acc = 0.f;
#pragma unroll
        for (int t = 0; t < 19; ++t) acc += F_G0[t] * A[t];
#pragma unroll
        for (int t = 0; t < 13; ++t) acc += F_G1[t] * B[t];
        outp[xbase + h * (WS * CH)] = acc;
#pragma unroll
        for (int t = 0; t < 18; ++t) A[t] = A[t + 1];
#pragma unroll
        for (int t = 0; t < 12; ++t) B[t] = B[t + 1];
        A[18] = ldA(symi(h + 10));
        B[12] = ldB(symi(h + 7));
    }
}

// ---- K4: inverse row filters (sliding window, no LDS) -> out
__global__ __launch_bounds__(256, 2) void k_inv_rows(const float* __restrict__ lo2,
                                                     const float* __restrict__ hi2,
                                                     float* __restrict__ out) {
    int b = blockIdx.x / HS, h = blockIdx.x % HS;
    int strip = threadIdx.x >> 6, c = threadIdx.x & 63;
    int base = (b * HS + h) * WS * CH + c;
    const float* rlo = lo2 + base;
    const float* rhi = hi2 + base;
    float* op = out + base;
    int w0s = strip * 14;
    float A[19], B[13];
#pragma unroll
    for (int t = 0; t < 19; ++t) A[t] = rlo[symi(w0s - 9 + t) * CH];
#pragma unroll
    for (int t = 0; t < 13; ++t) B[t] = rhi[symi(w0s - 6 + t) * CH];
#pragma unroll 7
    for (int k = 0; k < 14; ++k) {
        int w = w0s + k;
        float acc = 0.f;
#pragma unroll
        for (int t = 0; t < 19; ++t) acc += F_G0[t] * A[t];
#pragma unroll
        for (int t = 0; t < 13; ++t) acc += F_G1[t] * B[t];
        op[w * CH] = acc;
#pragma unroll
        for (int t = 0; t < 18; ++t) A[t] = A[t + 1];
#pragma unroll
        for (int t = 0; t < 12; ++t) B[t] = B[t + 1];
        A[18] = rlo[symi(w + 10) * CH];
        B[12] = rhi[symi(w + 7) * CH];
    }
}

extern "C" void kernel_launch(void* const* d_in, const int* in_sizes, int n_in,
                              void* d_out, int out_size, void* d_ws, size_t ws_size,
                              hipStream_t stream) {
    const float* x = (const float*)d_in[0];
    const float* w_ll = (const float*)d_in[1];
    const float* w1 = (const float*)d_in[2];
    const float* w2 = (const float*)d_in[3];
    const float* b1 = (const float*)d_in[4];
    const float* b2 = (const float*)d_in[5];
    float* out = (float*)d_out;

    const size_t plane = (size_t)BT * HS * WS * CH;  // 6,422,528 floats
    float* lo = (float*)d_ws;   // reused as lo2
    float* hi = lo + plane;     // reused as hi2
    float* xl = hi + plane;
    float* yh = xl + plane;     // [B][6][28][28][2][64]
    float* wllT = out;          // staged in d_out head (overwritten by k_inv_rows)

    k_wll_T<<<49, 256, 0, stream>>>(w_ll, wllT);
    k_fwd_rows<<<BT * HS, 256, 0, stream>>>(x, lo, hi);
    k_lo_mix<<<BT * WH, 256, 0, stream>>>(lo, wllT, w1, w2, b1, b2, xl, yh);
    k_hi_mix<<<BT * WH, 256, 0, stream>>>(hi, w1, w2, b1, b2, yh);
    k_inv_cols<<<dim3(BT * 14, 2), 256, 0, stream>>>(xl, yh, lo, hi);
    k_inv_rows<<<BT * HS, 256, 0, stream>>>(lo, hi, out);
}

// Round 6
// 541.402 us; speedup vs baseline: 1.1844x; 1.1844x over previous
//
#include <hip/hip_runtime.h>

#define BT 32
#define CH 64
#define HS 56
#define WS 56
#define HH 28
#define WH 28

// ---------------- filter constants (exact reference values) ----------------
namespace {
constexpr float ISQ2 = 0.70710678118654752440f;
constexpr float F_H0[13] = {-0.0017578125f, 0.0f, 0.022265625f, -0.046875f,
    -0.0482421875f, 0.296875f, 0.55546875f, 0.296875f, -0.0482421875f,
    -0.046875f, 0.022265625f, 0.0f, -0.0017578125f};
constexpr float F_H1[19] = {-7.0626e-05f, 0.0f, 0.00134189f, -0.00188341f,
    -0.0071566f, 0.023856f, 0.0556431f, -0.0516881f, -0.299758f, 0.559431f,
    -0.299758f, -0.0516881f, 0.0556431f, 0.023856f, -0.0071566f,
    -0.00188341f, 0.00134189f, 0.0f, -7.0626e-05f};
constexpr float F_G0[19] = {7.0626e-05f, 0.0f, -0.00134189f, -0.00188341f,
    0.0071566f, 0.023856f, -0.0556431f, -0.0516881f, 0.299758f, 0.559431f,
    0.299758f, -0.0516881f, -0.0556431f, 0.023856f, 0.0071566f,
    -0.00188341f, -0.00134189f, 0.0f, 7.0626e-05f};
constexpr float F_G1[13] = {-0.0017578125f, 0.0f, 0.022265625f, 0.046875f,
    -0.0482421875f, -0.296875f, 0.55546875f, -0.296875f, -0.0482421875f,
    0.046875f, 0.022265625f, 0.0f, -0.0017578125f};
}

__device__ __forceinline__ int symi(int k) {
    k = (k < 0) ? (-1 - k) : k;
    k = (k >= HS) ? (2 * HS - 1 - k) : k;
    return k;
}

__device__ __forceinline__ unsigned short f2bf(float f) {  // RNE bf16
    unsigned u = __float_as_uint(f);
    u += 0x7fffu + ((u >> 16) & 1u);
    return (unsigned short)(u >> 16);
}
__device__ __forceinline__ float bf2f(unsigned short h) {
    return __uint_as_float(((unsigned)h) << 16);
}

// sbT layout: plane p = s*2 + ri (12 planes), [p][c 64][b 32][pos 784], bf16
#define PPOS 784
#define PS (BT * PPOS)  // stride per c-step = 25088

// ---- K0: transpose w_ll [c][h][w] -> wllT [h][w][c] (staged in d_out head)
__global__ __launch_bounds__(256) void k_wll_T(const float* __restrict__ wll,
                                               float* __restrict__ wllT) {
    __shared__ float tile[64][65];
    int pos0 = blockIdx.x * 64;
    int lp = threadIdx.x & 63, g = threadIdx.x >> 6;
#pragma unroll
    for (int r = 0; r < 16; ++r) {
        int cc = r * 4 + g;
        tile[cc][lp] = wll[cc * (HS * WS) + pos0 + lp];
    }
    __syncthreads();
#pragma unroll
    for (int r = 0; r < 16; ++r) {
        int pl = r * 4 + g;
        wllT[(pos0 + pl) * CH + lp] = tile[lp][pl];
    }
}

// ---- K1: forward row filters (sliding window, no LDS): x -> lo, hi
__global__ __launch_bounds__(256) void k_fwd_rows(const float* __restrict__ x,
                                                  float* __restrict__ lo,
                                                  float* __restrict__ hi) {
    int b = blockIdx.x / HS, h = blockIdx.x % HS;
    int strip = threadIdx.x >> 6, c = threadIdx.x & 63;
    int base = (b * HS + h) * WS * CH + c;
    const float* row = x + base;
    float* lop = lo + base;
    float* hip = hi + base;
    int w0s = strip * 14;
    float W[19];
#pragma unroll
    for (int t = 0; t < 19; ++t) W[t] = row[symi(w0s - 9 + t) * CH];
    for (int k = 0; k < 14; ++k) {
        int w = w0s + k;
        float aLo = 0.f, aHi = 0.f;
#pragma unroll
        for (int t = 0; t < 13; ++t) aLo += F_H0[t] * W[3 + t];
#pragma unroll
        for (int t = 0; t < 19; ++t) aHi += F_H1[t] * W[t];
        lop[w * CH] = aLo;
        hip[w * CH] = aHi;
#pragma unroll
        for (int t = 0; t < 18; ++t) W[t] = W[t + 1];
        W[18] = row[symi(w + 10) * CH];
    }
}

// ---- K2a: lo column filters -> xl (fp32) + subband planes 0,1,10,11 (bf16)
__global__ __launch_bounds__(256) void k_cols_lo(
    const float* __restrict__ lo, const float* __restrict__ wllT,
    float* __restrict__ xl, unsigned short* __restrict__ sbT) {
    __shared__ float qT[4][64][28];  // 28.7 KB
    int b = blockIdx.x / WH, wp = blockIdx.x % WH;
    int w0 = 2 * wp, tid = threadIdx.x;
    int q = tid >> 6, c = tid & 63;
    int rp = q >> 1, jc = q & 1;
    const float* colbase = lo + (b * HS) * WS * CH + (w0 + jc) * CH + c;
    {
        float W[19];
#pragma unroll
        for (int t = 0; t < 19; ++t) W[t] = colbase[symi(rp - 9 + t) * (WS * CH)];
        for (int i = 0; i < 28; ++i) {
            int h = 2 * i + rp;
            float vll = 0.f, vlh = 0.f;
#pragma unroll
            for (int t = 0; t < 13; ++t) vll += F_H0[t] * W[3 + t];
#pragma unroll
            for (int t = 0; t < 19; ++t) vlh += F_H1[t] * W[t];
            xl[((b * HS + h) * WS + (w0 + jc)) * CH + c] =
                vll * wllT[(h * WS + (w0 + jc)) * CH + c];
            qT[q][c][i] = vlh;
#pragma unroll
            for (int t = 0; t < 17; ++t) W[t] = W[t + 2];
            W[17] = colbase[symi(h + 10) * (WS * CH)];
            W[18] = colbase[symi(h + 11) * (WS * CH)];
        }
    }
    __syncthreads();
    // fused q2c + bf16 pack + transposed store
    // j=q: 0:(a-d)->p0  1:(b+c)->p1  2:(a+d)->p10  3:(b-c)->p11
    int rowA = q & 1, rowB = 3 - (q & 1);
    float sgn = (q == 1 || q == 2) ? 1.f : -1.f;
    int p = (q < 2) ? q : q + 8;
    const float* qA = &qT[rowA][c][0];
    const float* qB = &qT[rowB][c][0];
    unsigned short* dst = sbT + ((p * 64 + c) * BT + b) * PPOS + wp * 28;
#pragma unroll
    for (int g = 0; g < 7; ++g) {
        float4 a4 = *(const float4*)(qA + g * 4);
        float4 b4 = *(const float4*)(qB + g * 4);
        float v0 = (a4.x + sgn * b4.x) * ISQ2;
        float v1 = (a4.y + sgn * b4.y) * ISQ2;
        float v2 = (a4.z + sgn * b4.z) * ISQ2;
        float v3 = (a4.w + sgn * b4.w) * ISQ2;
        uint2 pk;
        pk.x = (unsigned)f2bf(v0) | ((unsigned)f2bf(v1) << 16);
        pk.y = (unsigned)f2bf(v2) | ((unsigned)f2bf(v3) << 16);
        *(uint2*)(dst + g * 4) = pk;
    }
}

// ---- K2b: hi column filters -> subband planes 2..9 (bf16)
__global__ __launch_bounds__(256) void k_cols_hi(const float* __restrict__ hi,
                                                 unsigned short* __restrict__ sbT) {
    __shared__ float qT[2][4][64][28];  // 57.3 KB: [src 0=hl(H0) 1=hh(H1)][q][c][i]
    int b = blockIdx.x / WH, wp = blockIdx.x % WH;
    int w0 = 2 * wp, tid = threadIdx.x;
    int q = tid >> 6, c = tid & 63;
    int rp = q >> 1, jc = q & 1;
    const float* colbase = hi + (b * HS) * WS * CH + (w0 + jc) * CH + c;
    {
        float W[19];
#pragma unroll
        for (int t = 0; t < 19; ++t) W[t] = colbase[symi(rp - 9 + t) * (WS * CH)];
        for (int i = 0; i < 28; ++i) {
            int h = 2 * i + rp;
            float vhl = 0.f, vhh = 0.f;
#pragma unroll
            for (int t = 0; t < 13; ++t) vhl += F_H0[t] * W[3 + t];
#pragma unroll
            for (int t = 0; t < 19; ++t) vhh += F_H1[t] * W[t];
            qT[0][q][c][i] = vhl;
            qT[1][q][c][i] = vhh;
#pragma unroll
            for (int t = 0; t < 17; ++t) W[t] = W[t + 2];
            W[17] = colbase[symi(h + 10) * (WS * CH)];
            W[18] = colbase[symi(h + 11) * (WS * CH)];
        }
    }
    __syncthreads();
    int rowA = q & 1, rowB = 3 - (q & 1);
    float sgn = (q == 1 || q == 2) ? 1.f : -1.f;
#pragma unroll
    for (int src = 0; src < 2; ++src) {
        // src0 (hl): planes 4,5,6,7 (s2,s3); src1 (hh): planes 2,3,8,9 (s1,s4)
        int p = (src == 0) ? (4 + q) : ((q < 2) ? (2 + q) : (6 + q));
        const float* qA = &qT[src][rowA][c][0];
        const float* qB = &qT[src][rowB][c][0];
        unsigned short* dst = sbT + ((p * 64 + c) * BT + b) * PPOS + wp * 28;
#pragma unroll
        for (int g = 0; g < 7; ++g) {
            float4 a4 = *(const float4*)(qA + g * 4);
            float4 b4 = *(const float4*)(qB + g * 4);
            float v0 = (a4.x + sgn * b4.x) * ISQ2;
            float v1 = (a4.y + sgn * b4.y) * ISQ2;
            float v2 = (a4.z + sgn * b4.z) * ISQ2;
            float v3 = (a4.w + sgn * b4.w) * ISQ2;
            uint2 pk;
            pk.x = (unsigned)f2bf(v0) | ((unsigned)f2bf(v1) << 16);
            pk.y = (unsigned)f2bf(v2) | ((unsigned)f2bf(v3) << 16);
            *(uint2*)(dst + g * 4) = pk;
        }
    }
}

// ---- K3: channel mixing. wave = 64 consecutive positions, one nb per wave.
// BUGFIX vs R4/R5: imag bias offset is 64 (b1/b2 are (2,4,16)=128 elems), not 128.
// Loops d-outer/k-inner so the 16 k-weights per d are contiguous; nb is
// readfirstlane'd so weight addresses are wave-uniform (scalar s_load path).
__global__ __launch_bounds__(256) void k_mix(
    const unsigned short* __restrict__ sbT, const float* __restrict__ w1,
    const float* __restrict__ w2, const float* __restrict__ b1,
    const float* __restrict__ b2, float* __restrict__ yh) {
    int blk = blockIdx.x;
    int pb = blk % 13;
    int rem = blk / 13;
    int b = rem % BT;
    int sq = rem / BT;  // subband 0..5
    int tid = threadIdx.x;
    int lane = tid & 63;
    int nb = __builtin_amdgcn_readfirstlane(tid >> 6);
    int pos = pb * 64 + lane;
    bool ok = (pos < PPOS);
    int posc = ok ? pos : (PPOS - 1);

    int base0 = (((sq * 2 + 0) * 64 + nb * 16) * BT + b) * PPOS + posc;
    int base1 = base0 + 64 * PS;  // imag plane
    float xr[16], xi[16];
#pragma unroll
    for (int d = 0; d < 16; ++d) xr[d] = bf2f(sbT[base0 + d * PS]);
#pragma unroll
    for (int d = 0; d < 16; ++d) xi[d] = bf2f(sbT[base1 + d * PS]);

    const float* w1r = w1 + nb * 256;        // [d][k] contiguous in k
    const float* w1i = w1 + 1024 + nb * 256;
    float l1r[16], l1i[16];
#pragma unroll
    for (int k = 0; k < 16; ++k) {
        l1r[k] = b1[nb * 16 + k];
        l1i[k] = b1[64 + nb * 16 + k];
    }
#pragma unroll
    for (int d = 0; d < 16; ++d) {
        float ar = xr[d], ai = xi[d];
#pragma unroll
        for (int k = 0; k < 16; ++k) {
            float wr = w1r[d * 16 + k], wi = w1i[d * 16 + k];
            l1r[k] += ar * wr - ai * wi;
            l1i[k] += ar * wi + ai * wr;
        }
    }
#pragma unroll
    for (int k = 0; k < 16; ++k) {
        l1r[k] = fmaxf(l1r[k], 0.f);
        l1i[k] = fmaxf(l1i[k], 0.f);
    }

    const float* w2r = w2 + nb * 256;
    const float* w2i = w2 + 1024 + nb * 256;
    float o2r[16], o2i[16];
#pragma unroll
    for (int k = 0; k < 16; ++k) {
        o2r[k] = b2[nb * 16 + k];
        o2i[k] = b2[64 + nb * 16 + k];
    }
#pragma unroll
    for (int d = 0; d < 16; ++d) {
        float ar = l1r[d], ai = l1i[d];
#pragma unroll
        for (int k = 0; k < 16; ++k) {
            float wr = w2r[d * 16 + k], wi = w2i[d * 16 + k];
            o2r[k] += ar * wr - ai * wi;
            o2i[k] += ar * wi + ai * wr;
        }
    }

    int wp = pos / 28, i = pos - wp * 28;
    int o = ((((b * 6 + sq) * HH + i) * WH + wp) * 2) * CH + nb * 16;
    if (ok) {
#pragma unroll
        for (int k = 0; k < 16; ++k) {
            yh[o + k] = o2r[k];
            yh[o + CH + k] = o2i[k];
        }
    }
}

// ---- K4: inverse column filters (sliding window, no LDS, c2q on the fly)
__global__ __launch_bounds__(256) void k_inv_cols(const float* __restrict__ xl,
                                                  const float* __restrict__ yh,
                                                  float* __restrict__ lo2,
                                                  float* __restrict__ hi2) {
    int mode = blockIdx.y;
    int b = blockIdx.x / 14, wg = blockIdx.x % 14;
    int wl = threadIdx.x >> 6, c = threadIdx.x & 63;
    int w = wg * 4 + wl, wp = w >> 1, jw = w & 1;
    const int stepi = WH * 2 * CH;  // 3584
    int cbase = wp * 2 * CH + c;

    int baseA1 = 0, baseA2 = 0, baseB1, baseB2;
    if (mode == 0) {
        baseB1 = ((b * 6 + 0) * HH) * stepi + cbase;
        baseB2 = ((b * 6 + 5) * HH) * stepi + cbase;
    } else {
        baseA1 = ((b * 6 + 2) * HH) * stepi + cbase;
        baseA2 = ((b * 6 + 3) * HH) * stepi + cbase;
        baseB1 = ((b * 6 + 1) * HH) * stepi + cbase;
        baseB2 = ((b * 6 + 4) * HH) * stepi + cbase;
    }
    int xbase = (b * HS) * WS * CH + w * CH + c;

    auto c2q = [&](int b1_, int b2_, int r) -> float {
        int i = r >> 1, sel = (r & 1) ^ jw;
        float u = yh[b1_ + i * stepi + sel * CH];
        float v = yh[b2_ + i * stepi + sel * CH];
        float val = ((r & 1) == 0) ? (u + v) : ((jw == 0) ? (u - v) : (v - u));
        return val * ISQ2;
    };
    auto ldA = [&](int r) -> float {
        if (mode == 0) return xl[xbase + r * (WS * CH)];
        return c2q(baseA1, baseA2, r);
    };
    auto ldB = [&](int r) -> float { return c2q(baseB1, baseB2, r); };
    float* outp = mode ? hi2 : lo2;

    float A[19], B[13];
#pragma unroll
    for (int t = 0; t < 19; ++t) A[t] = ldA(symi(t - 9));
#pragma unroll
    for (int t = 0; t < 13; ++t) B[t] = ldB(symi(t - 6));
    for (int h = 0; h < 56; ++h) {
        float acc = 0.f;
#pragma unroll
        for (int t = 0; t < 19; ++t) acc += F_G0[t] * A[t];
#pragma unroll
        for (int t = 0; t < 13; ++t) acc += F_G1[t] * B[t];
        outp[xbase + h * (WS * CH)] = acc;
#pragma unroll
        for (int t = 0; t < 18; ++t) A[t] = A[t + 1];
#pragma unroll
        for (int t = 0; t < 12; ++t) B[t] = B[t + 1];
        A[18] = ldA(symi(h + 10));
        B[12] = ldB(symi(h + 7));
    }
}

// ---- K5: inverse row filters (sliding window, no LDS) -> out
__global__ __launch_bounds__(256) void k_inv_rows(const float* __restrict__ lo2,
                                                  const float* __restrict__ hi2,
                                                  float* __restrict__ out) {
    int b = blockIdx.x / HS, h = blockIdx.x % HS;
    int strip = threadIdx.x >> 6, c = threadIdx.x & 63;
    int base = (b * HS + h) * WS * CH + c;
    const float* rlo = lo2 + base;
    const float* rhi = hi2 + base;
    float* op = out + base;
    int w0s = strip * 14;
    float A[19], B[13];
#pragma unroll
    for (int t = 0; t < 19; ++t) A[t] = rlo[symi(w0s - 9 + t) * CH];
#pragma unroll
    for (int t = 0; t < 13; ++t) B[t] = rhi[symi(w0s - 6 + t) * CH];
    for (int k = 0; k < 14; ++k) {
        int w = w0s + k;
        float acc = 0.f;
#pragma unroll
        for (int t = 0; t < 19; ++t) acc += F_G0[t] * A[t];
#pragma unroll
        for (int t = 0; t < 13; ++t) acc += F_G1[t] * B[t];
        op[w * CH] = acc;
#pragma unroll
        for (int t = 0; t < 18; ++t) A[t] = A[t + 1];
#pragma unroll
        for (int t = 0; t < 12; ++t) B[t] = B[t + 1];
        A[18] = rlo[symi(w + 10) * CH];
        B[12] = rhi[symi(w + 7) * CH];
    }
}

extern "C" void kernel_launch(void* const* d_in, const int* in_sizes, int n_in,
                              void* d_out, int out_size, void* d_ws, size_t ws_size,
                              hipStream_t stream) {
    const float* x = (const float*)d_in[0];
    const float* w_ll = (const float*)d_in[1];
    const float* w1 = (const float*)d_in[2];
    const float* w2 = (const float*)d_in[3];
    const float* b1 = (const float*)d_in[4];
    const float* b2 = (const float*)d_in[5];
    float* out = (float*)d_out;

    // workspace map (floats), total 38,535,168 fl = 154.1 MB (R1-proven size)
    const size_t plane = (size_t)BT * HS * WS * CH;        // 6,422,528
    const size_t yhsz = (size_t)BT * 6 * HH * WH * 2 * CH; // 19,267,584
    float* wsf = (float*)d_ws;
    float* lo = wsf;                      // dead after k_cols_lo
    float* hi = wsf + plane;              // dead after k_cols_hi
    float* yh = wsf;                      // [0, yhsz) overwrites lo/hi (dead by then)
    float* xl = wsf + yhsz;               // survives to k_inv_cols
    unsigned short* sbT = (unsigned short*)(wsf + yhsz + plane);  // 38.5 MB bf16
    float* lo2 = wsf + yhsz + plane;      // overwrites sbT (dead after k_mix)
    float* hi2 = lo2 + plane;

    float* wllT = out;  // staged in d_out head (overwritten by k_inv_rows)

    k_wll_T<<<49, 256, 0, stream>>>(w_ll, wllT);
    k_fwd_rows<<<BT * HS, 256, 0, stream>>>(x, lo, hi);
    k_cols_lo<<<BT * WH, 256, 0, stream>>>(lo, wllT, xl, sbT);
    k_cols_hi<<<BT * WH, 256, 0, stream>>>(hi, sbT);
    k_mix<<<6 * BT * 13, 256, 0, stream>>>(sbT, w1, w2, b1, b2, yh);
    k_inv_cols<<<dim3(BT * 14, 2), 256, 0, stream>>>(xl, yh, lo2, hi2);
    k_inv_rows<<<BT * HS, 256, 0, stream>>>(lo2, hi2, out);
}

// Round 7
// 250.005 us; speedup vs baseline: 2.5649x; 2.1656x over previous
//
#include <hip/hip_runtime.h>

#define BT 32
#define CH 64
#define HS 56
#define WS 56
#define HH 28
#define WH 28

// ---------------- filter constants (exact reference values) ----------------
namespace {
constexpr float ISQ2 = 0.70710678118654752440f;
constexpr float F_H0[13] = {-0.0017578125f, 0.0f, 0.022265625f, -0.046875f,
    -0.0482421875f, 0.296875f, 0.55546875f, 0.296875f, -0.0482421875f,
    -0.046875f, 0.022265625f, 0.0f, -0.0017578125f};
constexpr float F_H1[19] = {-7.0626e-05f, 0.0f, 0.00134189f, -0.00188341f,
    -0.0071566f, 0.023856f, 0.0556431f, -0.0516881f, -0.299758f, 0.559431f,
    -0.299758f, -0.0516881f, 0.0556431f, 0.023856f, -0.0071566f,
    -0.00188341f, 0.00134189f, 0.0f, -7.0626e-05f};
constexpr float F_G0[19] = {7.0626e-05f, 0.0f, -0.00134189f, -0.00188341f,
    0.0071566f, 0.023856f, -0.0556431f, -0.0516881f, 0.299758f, 0.559431f,
    0.299758f, -0.0516881f, -0.0556431f, 0.023856f, 0.0071566f,
    -0.00188341f, -0.00134189f, 0.0f, 7.0626e-05f};
constexpr float F_G1[13] = {-0.0017578125f, 0.0f, 0.022265625f, 0.046875f,
    -0.0482421875f, -0.296875f, 0.55546875f, -0.296875f, -0.0482421875f,
    0.046875f, 0.022265625f, 0.0f, -0.0017578125f};
}

__device__ __forceinline__ int symi(int k) {
    k = (k < 0) ? (-1 - k) : k;
    k = (k >= HS) ? (2 * HS - 1 - k) : k;
    return k;
}

__device__ __forceinline__ unsigned short f2bf(float f) {  // RNE bf16
    unsigned u = __float_as_uint(f);
    u += 0x7fffu + ((u >> 16) & 1u);
    return (unsigned short)(u >> 16);
}
__device__ __forceinline__ float bf2f(unsigned short h) {
    return __uint_as_float(((unsigned)h) << 16);
}

typedef __attribute__((ext_vector_type(8))) short short8;  // 8 bf16 (4 VGPR)
typedef __attribute__((ext_vector_type(4))) float f32x4;

// sbT layout: plane p = s*2 + ri (12 planes), [p][c 64][b 32][pos 784], bf16
#define PPOS 784
#define PS (BT * PPOS)  // stride per c-step = 25088

// ---- K0: transpose w_ll [c][h][w] -> wllT [h][w][c] (staged in d_out head)
__global__ __launch_bounds__(256) void k_wll_T(const float* __restrict__ wll,
                                               float* __restrict__ wllT) {
    __shared__ float tile[64][65];
    int pos0 = blockIdx.x * 64;
    int lp = threadIdx.x & 63, g = threadIdx.x >> 6;
#pragma unroll
    for (int r = 0; r < 16; ++r) {
        int cc = r * 4 + g;
        tile[cc][lp] = wll[cc * (HS * WS) + pos0 + lp];
    }
    __syncthreads();
#pragma unroll
    for (int r = 0; r < 16; ++r) {
        int pl = r * 4 + g;
        wllT[(pos0 + pl) * CH + lp] = tile[lp][pl];
    }
}

// ---- K1: forward row filters (sliding window, no LDS): x -> lo, hi
__global__ __launch_bounds__(256) void k_fwd_rows(const float* __restrict__ x,
                                                  float* __restrict__ lo,
                                                  float* __restrict__ hi) {
    int b = blockIdx.x / HS, h = blockIdx.x % HS;
    int strip = threadIdx.x >> 6, c = threadIdx.x & 63;
    int base = (b * HS + h) * WS * CH + c;
    const float* row = x + base;
    float* lop = lo + base;
    float* hip = hi + base;
    int w0s = strip * 14;
    float W[19];
#pragma unroll
    for (int t = 0; t < 19; ++t) W[t] = row[symi(w0s - 9 + t) * CH];
    for (int k = 0; k < 14; ++k) {
        int w = w0s + k;
        float aLo = 0.f, aHi = 0.f;
#pragma unroll
        for (int t = 0; t < 13; ++t) aLo += F_H0[t] * W[3 + t];
#pragma unroll
        for (int t = 0; t < 19; ++t) aHi += F_H1[t] * W[t];
        lop[w * CH] = aLo;
        hip[w * CH] = aHi;
#pragma unroll
        for (int t = 0; t < 18; ++t) W[t] = W[t + 1];
        W[18] = row[symi(w + 10) * CH];
    }
}

// ---- K2a: lo column filters -> xl (fp32) + subband planes 0,1,10,11 (bf16)
__global__ __launch_bounds__(256) void k_cols_lo(
    const float* __restrict__ lo, const float* __restrict__ wllT,
    float* __restrict__ xl, unsigned short* __restrict__ sbT) {
    __shared__ float qT[4][64][28];  // 28.7 KB
    int b = blockIdx.x / WH, wp = blockIdx.x % WH;
    int w0 = 2 * wp, tid = threadIdx.x;
    int q = tid >> 6, c = tid & 63;
    int rp = q >> 1, jc = q & 1;
    const float* colbase = lo + (b * HS) * WS * CH + (w0 + jc) * CH + c;
    {
        float W[19];
#pragma unroll
        for (int t = 0; t < 19; ++t) W[t] = colbase[symi(rp - 9 + t) * (WS * CH)];
        for (int i = 0; i < 28; ++i) {
            int h = 2 * i + rp;
            float vll = 0.f, vlh = 0.f;
#pragma unroll
            for (int t = 0; t < 13; ++t) vll += F_H0[t] * W[3 + t];
#pragma unroll
            for (int t = 0; t < 19; ++t) vlh += F_H1[t] * W[t];
            xl[((b * HS + h) * WS + (w0 + jc)) * CH + c] =
                vll * wllT[(h * WS + (w0 + jc)) * CH + c];
            qT[q][c][i] = vlh;
#pragma unroll
            for (int t = 0; t < 17; ++t) W[t] = W[t + 2];
            W[17] = colbase[symi(h + 10) * (WS * CH)];
            W[18] = colbase[symi(h + 11) * (WS * CH)];
        }
    }
    __syncthreads();
    // fused q2c + bf16 pack + transposed store
    // j=q: 0:(a-d)->p0  1:(b+c)->p1  2:(a+d)->p10  3:(b-c)->p11
    int rowA = q & 1, rowB = 3 - (q & 1);
    float sgn = (q == 1 || q == 2) ? 1.f : -1.f;
    int p = (q < 2) ? q : q + 8;
    const float* qA = &qT[rowA][c][0];
    const float* qB = &qT[rowB][c][0];
    unsigned short* dst = sbT + ((p * 64 + c) * BT + b) * PPOS + wp * 28;
#pragma unroll
    for (int g = 0; g < 7; ++g) {
        float4 a4 = *(const float4*)(qA + g * 4);
        float4 b4 = *(const float4*)(qB + g * 4);
        float v0 = (a4.x + sgn * b4.x) * ISQ2;
        float v1 = (a4.y + sgn * b4.y) * ISQ2;
        float v2 = (a4.z + sgn * b4.z) * ISQ2;
        float v3 = (a4.w + sgn * b4.w) * ISQ2;
        uint2 pk;
        pk.x = (unsigned)f2bf(v0) | ((unsigned)f2bf(v1) << 16);
        pk.y = (unsigned)f2bf(v2) | ((unsigned)f2bf(v3) << 16);
        *(uint2*)(dst + g * 4) = pk;
    }
}

// ---- K2b: hi column filters -> subband planes 2..9 (bf16)
__global__ __launch_bounds__(256) void k_cols_hi(const float* __restrict__ hi,
                                                 unsigned short* __restrict__ sbT) {
    __shared__ float qT[2][4][64][28];  // 57.3 KB: [src 0=hl(H0) 1=hh(H1)][q][c][i]
    int b = blockIdx.x / WH, wp = blockIdx.x % WH;
    int w0 = 2 * wp, tid = threadIdx.x;
    int q = tid >> 6, c = tid & 63;
    int rp = q >> 1, jc = q & 1;
    const float* colbase = hi + (b * HS) * WS * CH + (w0 + jc) * CH + c;
    {
        float W[19];
#pragma unroll
        for (int t = 0; t < 19; ++t) W[t] = colbase[symi(rp - 9 + t) * (WS * CH)];
        for (int i = 0; i < 28; ++i) {
            int h = 2 * i + rp;
            float vhl = 0.f, vhh = 0.f;
#pragma unroll
            for (int t = 0; t < 13; ++t) vhl += F_H0[t] * W[3 + t];
#pragma unroll
            for (int t = 0; t < 19; ++t) vhh += F_H1[t] * W[t];
            qT[0][q][c][i] = vhl;
            qT[1][q][c][i] = vhh;
#pragma unroll
            for (int t = 0; t < 17; ++t) W[t] = W[t + 2];
            W[17] = colbase[symi(h + 10) * (WS * CH)];
            W[18] = colbase[symi(h + 11) * (WS * CH)];
        }
    }
    __syncthreads();
    int rowA = q & 1, rowB = 3 - (q & 1);
    float sgn = (q == 1 || q == 2) ? 1.f : -1.f;
#pragma unroll
    for (int src = 0; src < 2; ++src) {
        // src0 (hl): planes 4,5,6,7 (s2,s3); src1 (hh): planes 2,3,8,9 (s1,s4)
        int p = (src == 0) ? (4 + q) : ((q < 2) ? (2 + q) : (6 + q));
        const float* qA = &qT[src][rowA][c][0];
        const float* qB = &qT[src][rowB][c][0];
        unsigned short* dst = sbT + ((p * 64 + c) * BT + b) * PPOS + wp * 28;
#pragma unroll
        for (int g = 0; g < 7; ++g) {
            float4 a4 = *(const float4*)(qA + g * 4);
            float4 b4 = *(const float4*)(qB + g * 4);
            float v0 = (a4.x + sgn * b4.x) * ISQ2;
            float v1 = (a4.y + sgn * b4.y) * ISQ2;
            float v2 = (a4.z + sgn * b4.z) * ISQ2;
            float v3 = (a4.w + sgn * b4.w) * ISQ2;
            uint2 pk;
            pk.x = (unsigned)f2bf(v0) | ((unsigned)f2bf(v1) << 16);
            pk.y = (unsigned)f2bf(v2) | ((unsigned)f2bf(v3) << 16);
            *(uint2*)(dst + g * 4) = pk;
        }
    }
}

// ---- K3: channel mixing via MFMA. Complex 16x16 layer = two real
// mfma_f32_16x16x32_bf16 with K=32 = [real d | imag d]:
//   l1r = [xr|xi]·[w1r;-w1i]+b1r ; l1i = [xr|xi]·[w1i;w1r]+b1i (bias in C).
// Block = (sq, b, chunk of 112 pos); wave = nb; 7 MFMA tiles of 16 pos.
// Layer1 D-layout -> layer2 A-layout via per-wave LDS bounce.
__global__ __launch_bounds__(256) void k_mix(
    const unsigned short* __restrict__ sbT, const float* __restrict__ w1,
    const float* __restrict__ w2, const float* __restrict__ b1,
    const float* __restrict__ b2, float* __restrict__ yh) {
    __shared__ unsigned short l1buf[4][16][36];  // [wave][pos][k2 32 pad36]
    int blk = blockIdx.x;
    int sq = blk / (BT * 7);
    int rem = blk % (BT * 7);
    int b = rem / 7;
    int chunk = rem % 7;
    int tid = threadIdx.x;
    int lane = tid & 63;
    int wv = tid >> 6;
    int nb = __builtin_amdgcn_readfirstlane(wv);
    int quad = lane >> 4;
    int n = lane & 15;  // A: row m; B: col n; D: col n

    // weight fragments (B-operand): lane holds B[k=quad*8+j][n]
    short8 B1r, B1i, B2r, B2i;
#pragma unroll
    for (int j = 0; j < 8; ++j) {
        int kk = quad * 8 + j;
        int riw = kk >> 4, dd = kk & 15;
        float v1r = w1[nb * 256 + dd * 16 + n];
        float v1i = w1[1024 + nb * 256 + dd * 16 + n];
        float v2r = w2[nb * 256 + dd * 16 + n];
        float v2i = w2[1024 + nb * 256 + dd * 16 + n];
        B1r[j] = (short)f2bf(riw ? -v1i : v1r);
        B1i[j] = (short)f2bf(riw ? v1r : v1i);
        B2r[j] = (short)f2bf(riw ? -v2i : v2r);
        B2i[j] = (short)f2bf(riw ? v2r : v2i);
    }
    float bias1r = b1[nb * 16 + n], bias1i = b1[64 + nb * 16 + n];
    float bias2r = b2[nb * 16 + n], bias2i = b2[64 + nb * 16 + n];

    int pbase = chunk * 112;
    for (int t = 0; t < 7; ++t) {
        int pos0 = pbase + t * 16;
        // A1: lane holds A[m=n][k=quad*8+j]; k<16 -> real plane, else imag
        short8 A1;
#pragma unroll
        for (int j = 0; j < 8; ++j) {
            int kk = quad * 8 + j;
            int rix = kk >> 4, dd = kk & 15;
            int p = sq * 2 + rix, c = nb * 16 + dd;
            A1[j] = (short)sbT[((p * 64 + c) * BT + b) * PPOS + pos0 + n];
        }
        f32x4 acc1r = {bias1r, bias1r, bias1r, bias1r};
        f32x4 acc1i = {bias1i, bias1i, bias1i, bias1i};
        acc1r = __builtin_amdgcn_mfma_f32_16x16x32_bf16(A1, B1r, acc1r, 0, 0, 0);
        acc1i = __builtin_amdgcn_mfma_f32_16x16x32_bf16(A1, B1i, acc1i, 0, 0, 0);
        // relu + bf16 + LDS: lane holds D rows pos=quad*4+r, col n
#pragma unroll
        for (int r = 0; r < 4; ++r) {
            int pos = quad * 4 + r;
            l1buf[wv][pos][n] = f2bf(fmaxf(acc1r[r], 0.f));
            l1buf[wv][pos][16 + n] = f2bf(fmaxf(acc1i[r], 0.f));
        }
        __syncthreads();
        // A2: lane reads row m=n, k2 = quad*8..quad*8+7 (16B, 8B-aligned)
        union { short8 s8; uint2 u2[2]; } a2;
        const unsigned short* rowp = &l1buf[wv][n][0];
        a2.u2[0] = *(const uint2*)(rowp + quad * 8);
        a2.u2[1] = *(const uint2*)(rowp + quad * 8 + 4);
        f32x4 acc2r = {bias2r, bias2r, bias2r, bias2r};
        f32x4 acc2i = {bias2i, bias2i, bias2i, bias2i};
        acc2r = __builtin_amdgcn_mfma_f32_16x16x32_bf16(a2.s8, B2r, acc2r, 0, 0, 0);
        acc2i = __builtin_amdgcn_mfma_f32_16x16x32_bf16(a2.s8, B2i, acc2i, 0, 0, 0);
#pragma unroll
        for (int r = 0; r < 4; ++r) {
            int pos_g = pos0 + quad * 4 + r;
            int wp = pos_g / 28, ii = pos_g - wp * 28;
            int o = ((((b * 6 + sq) * HH + ii) * WH + wp) * 2) * CH + nb * 16 + n;
            yh[o] = acc2r[r];
            yh[o + CH] = acc2i[r];
        }
        __syncthreads();
    }
}

// ---- K4: inverse column filters (sliding window, no LDS, c2q on the fly)
__global__ __launch_bounds__(256) void k_inv_cols(const float* __restrict__ xl,
                                                  const float* __restrict__ yh,
                                                  float* __restrict__ lo2,
                                                  float* __restrict__ hi2) {
    int mode = blockIdx.y;
    int b = blockIdx.x / 14, wg = blockIdx.x % 14;
    int wl = threadIdx.x >> 6, c = threadIdx.x & 63;
    int w = wg * 4 + wl, wp = w >> 1, jw = w & 1;
    const int stepi = WH * 2 * CH;  // 3584
    int cbase = wp * 2 * CH + c;

    int baseA1 = 0, baseA2 = 0, baseB1, baseB2;
    if (mode == 0) {
        baseB1 = ((b * 6 + 0) * HH) * stepi + cbase;
        baseB2 = ((b * 6 + 5) * HH) * stepi + cbase;
    } else {
        baseA1 = ((b * 6 + 2) * HH) * stepi + cbase;
        baseA2 = ((b * 6 + 3) * HH) * stepi + cbase;
        baseB1 = ((b * 6 + 1) * HH) * stepi + cbase;
        baseB2 = ((b * 6 + 4) * HH) * stepi + cbase;
    }
    int xbase = (b * HS) * WS * CH + w * CH + c;

    auto c2q = [&](int b1_, int b2_, int r) -> float {
        int i = r >> 1, sel = (r & 1) ^ jw;
        float u = yh[b1_ + i * stepi + sel * CH];
        float v = yh[b2_ + i * stepi + sel * CH];
        float val = ((r & 1) == 0) ? (u + v) : ((jw == 0) ? (u - v) : (v - u));
        return val * ISQ2;
    };
    auto ldA = [&](int r) -> float {
        if (mode == 0) return xl[xbase + r * (WS * CH)];
        return c2q(baseA1, baseA2, r);
    };
    auto ldB = [&](int r) -> float { return c2q(baseB1, baseB2, r); };
    float* outp = mode ? hi2 : lo2;

    float A[19], B[13];
#pragma unroll
    for (int t = 0; t < 19; ++t) A[t] = ldA(symi(t - 9));
#pragma unroll
    for (int t = 0; t < 13; ++t) B[t] = ldB(symi(t - 6));
    for (int h = 0; h < 56; ++h) {
        float acc = 0.f;
#pragma unroll
        for (int t = 0; t < 19; ++t) acc += F_G0[t] * A[t];
#pragma unroll
        for (int t = 0; t < 13; ++t) acc += F_G1[t] * B[t];
        outp[xbase + h * (WS * CH)] = acc;
#pragma unroll
        for (int t = 0; t < 18; ++t) A[t] = A[t + 1];
#pragma unroll
        for (int t = 0; t < 12; ++t) B[t] = B[t + 1];
        A[18] = ldA(symi(h + 10));
        B[12] = ldB(symi(h + 7));
    }
}

// ---- K5: inverse row filters (sliding window, no LDS) -> out
__global__ __launch_bounds__(256) void k_inv_rows(const float* __restrict__ lo2,
                                                  const float* __restrict__ hi2,
                                                  float* __restrict__ out) {
    int b = blockIdx.x / HS, h = blockIdx.x % HS;
    int strip = threadIdx.x >> 6, c = threadIdx.x & 63;
    int base = (b * HS + h) * WS * CH + c;
    const float* rlo = lo2 + base;
    const float* rhi = hi2 + base;
    float* op = out + base;
    int w0s = strip * 14;
    float A[19], B[13];
#pragma unroll
    for (int t = 0; t < 19; ++t) A[t] = rlo[symi(w0s - 9 + t) * CH];
#pragma unroll
    for (int t = 0; t < 13; ++t) B[t] = rhi[symi(w0s - 6 + t) * CH];
    for (int k = 0; k < 14; ++k) {
        int w = w0s + k;
        float acc = 0.f;
#pragma unroll
        for (int t = 0; t < 19; ++t) acc += F_G0[t] * A[t];
#pragma unroll
        for (int t = 0; t < 13; ++t) acc += F_G1[t] * B[t];
        op[w * CH] = acc;
#pragma unroll
        for (int t = 0; t < 18; ++t) A[t] = A[t + 1];
#pragma unroll
        for (int t = 0; t < 12; ++t) B[t] = B[t + 1];
        A[18] = rlo[symi(w + 10) * CH];
        B[12] = rhi[symi(w + 7) * CH];
    }
}

extern "C" void kernel_launch(void* const* d_in, const int* in_sizes, int n_in,
                              void* d_out, int out_size, void* d_ws, size_t ws_size,
                              hipStream_t stream) {
    const float* x = (const float*)d_in[0];
    const float* w_ll = (const float*)d_in[1];
    const float* w1 = (const float*)d_in[2];
    const float* w2 = (const float*)d_in[3];
    const float* b1 = (const float*)d_in[4];
    const float* b2 = (const float*)d_in[5];
    float* out = (float*)d_out;

    // workspace map (floats), total 38,535,168 fl = 154.1 MB (R1-proven size)
    const size_t plane = (size_t)BT * HS * WS * CH;        // 6,422,528
    const size_t yhsz = (size_t)BT * 6 * HH * WH * 2 * CH; // 19,267,584
    float* wsf = (float*)d_ws;
    float* lo = wsf;                      // dead after k_cols_lo
    float* hi = wsf + plane;              // dead after k_cols_hi
    float* yh = wsf;                      // [0, yhsz) overwrites lo/hi (dead by then)
    float* xl = wsf + yhsz;               // survives to k_inv_cols
    unsigned short* sbT = (unsigned short*)(wsf + yhsz + plane);  // 38.5 MB bf16
    float* lo2 = wsf + yhsz + plane;      // overwrites sbT (dead after k_mix)
    float* hi2 = lo2 + plane;

    float* wllT = out;  // staged in d_out head (overwritten by k_inv_rows)

    k_wll_T<<<49, 256, 0, stream>>>(w_ll, wllT);
    k_fwd_rows<<<BT * HS, 256, 0, stream>>>(x, lo, hi);
    k_cols_lo<<<BT * WH, 256, 0, stream>>>(lo, wllT, xl, sbT);
    k_cols_hi<<<BT * WH, 256, 0, stream>>>(hi, sbT);
    k_mix<<<6 * BT * 7, 256, 0, stream>>>(sbT, w1, w2, b1, b2, yh);
    k_inv_cols<<<dim3(BT * 14, 2), 256, 0, stream>>>(xl, yh, lo2, hi2);
    k_inv_rows<<<BT * HS, 256, 0, stream>>>(lo2, hi2, out);
}

// Round 8
// 220.804 us; speedup vs baseline: 2.9041x; 1.1322x over previous
//
#include <hip/hip_runtime.h>

#define BT 32
#define CH 64
#define HS 56
#define WS 56
#define HH 28
#define WH 28

// ---------------- filter constants (exact reference values) ----------------
namespace {
constexpr float ISQ2 = 0.70710678118654752440f;
constexpr float F_H0[13] = {-0.0017578125f, 0.0f, 0.022265625f, -0.046875f,
    -0.0482421875f, 0.296875f, 0.55546875f, 0.296875f, -0.0482421875f,
    -0.046875f, 0.022265625f, 0.0f, -0.0017578125f};
constexpr float F_H1[19] = {-7.0626e-05f, 0.0f, 0.00134189f, -0.00188341f,
    -0.0071566f, 0.023856f, 0.0556431f, -0.0516881f, -0.299758f, 0.559431f,
    -0.299758f, -0.0516881f, 0.0556431f, 0.023856f, -0.0071566f,
    -0.00188341f, 0.00134189f, 0.0f, -7.0626e-05f};
constexpr float F_G0[19] = {7.0626e-05f, 0.0f, -0.00134189f, -0.00188341f,
    0.0071566f, 0.023856f, -0.0556431f, -0.0516881f, 0.299758f, 0.559431f,
    0.299758f, -0.0516881f, -0.0556431f, 0.023856f, 0.0071566f,
    -0.00188341f, -0.00134189f, 0.0f, 7.0626e-05f};
constexpr float F_G1[13] = {-0.0017578125f, 0.0f, 0.022265625f, 0.046875f,
    -0.0482421875f, -0.296875f, 0.55546875f, -0.296875f, -0.0482421875f,
    0.046875f, 0.022265625f, 0.0f, -0.0017578125f};
}

__device__ __forceinline__ int symi(int k) {
    k = (k < 0) ? (-1 - k) : k;
    k = (k >= HS) ? (2 * HS - 1 - k) : k;
    return k;
}

__device__ __forceinline__ unsigned short f2bf(float f) {  // RNE bf16
    unsigned u = __float_as_uint(f);
    u += 0x7fffu + ((u >> 16) & 1u);
    return (unsigned short)(u >> 16);
}

typedef __attribute__((ext_vector_type(8))) short short8;  // 8 bf16 (4 VGPR)
typedef __attribute__((ext_vector_type(4))) float f32x4;

// sbT layout: plane p = s*2 + ri (12 planes), [p][c 64][b 32][pos 784], bf16
#define PPOS 784
#define PS (BT * PPOS)  // stride per c-step = 25088

// ---- K0: transpose w_ll [c][h][w] -> wllT [h][w][c] (staged in d_out head)
__global__ __launch_bounds__(256) void k_wll_T(const float* __restrict__ wll,
                                               float* __restrict__ wllT) {
    __shared__ float tile[64][65];
    int pos0 = blockIdx.x * 64;
    int lp = threadIdx.x & 63, g = threadIdx.x >> 6;
#pragma unroll
    for (int r = 0; r < 16; ++r) {
        int cc = r * 4 + g;
        tile[cc][lp] = wll[cc * (HS * WS) + pos0 + lp];
    }
    __syncthreads();
#pragma unroll
    for (int r = 0; r < 16; ++r) {
        int pl = r * 4 + g;
        wllT[(pos0 + pl) * CH + lp] = tile[lp][pl];
    }
}

// ---- K1: forward row filters (sliding window, no LDS): x -> lo, hi
__global__ __launch_bounds__(256) void k_fwd_rows(const float* __restrict__ x,
                                                  float* __restrict__ lo,
                                                  float* __restrict__ hi) {
    int b = blockIdx.x / HS, h = blockIdx.x % HS;
    int strip = threadIdx.x >> 6, c = threadIdx.x & 63;
    int base = (b * HS + h) * WS * CH + c;
    const float* row = x + base;
    float* lop = lo + base;
    float* hip = hi + base;
    int w0s = strip * 14;
    float W[19];
#pragma unroll
    for (int t = 0; t < 19; ++t) W[t] = row[symi(w0s - 9 + t) * CH];
#pragma unroll
    for (int k = 0; k < 14; ++k) {
        int w = w0s + k;
        float aLo = 0.f, aHi = 0.f;
#pragma unroll
        for (int t = 0; t < 13; ++t) aLo += F_H0[t] * W[3 + t];
#pragma unroll
        for (int t = 0; t < 19; ++t) aHi += F_H1[t] * W[t];
        lop[w * CH] = aLo;
        hip[w * CH] = aHi;
#pragma unroll
        for (int t = 0; t < 18; ++t) W[t] = W[t + 1];
        W[18] = row[symi(w + 10) * CH];
    }
}

// ---- K2a: lo column filters -> xl (fp32) + subband planes 0,1,10,11 (bf16)
__global__ __launch_bounds__(256) void k_cols_lo(
    const float* __restrict__ lo, const float* __restrict__ wllT,
    float* __restrict__ xl, unsigned short* __restrict__ sbT) {
    __shared__ float qT[4][64][29];  // pad 29: conflict-free (gcd(29,32)=1)
    int b = blockIdx.x / WH, wp = blockIdx.x % WH;
    int w0 = 2 * wp, tid = threadIdx.x;
    int q = tid >> 6, c = tid & 63;
    int rp = q >> 1, jc = q & 1;
    const float* colbase = lo + (b * HS) * WS * CH + (w0 + jc) * CH + c;
    {
        float W[19];
#pragma unroll
        for (int t = 0; t < 19; ++t) W[t] = colbase[symi(rp - 9 + t) * (WS * CH)];
#pragma unroll
        for (int i = 0; i < 28; ++i) {
            int h = 2 * i + rp;
            float vll = 0.f, vlh = 0.f;
#pragma unroll
            for (int t = 0; t < 13; ++t) vll += F_H0[t] * W[3 + t];
#pragma unroll
            for (int t = 0; t < 19; ++t) vlh += F_H1[t] * W[t];
            xl[((b * HS + h) * WS + (w0 + jc)) * CH + c] =
                vll * wllT[(h * WS + (w0 + jc)) * CH + c];
            qT[q][c][i] = vlh;
#pragma unroll
            for (int t = 0; t < 17; ++t) W[t] = W[t + 2];
            W[17] = colbase[symi(h + 10) * (WS * CH)];
            W[18] = colbase[symi(h + 11) * (WS * CH)];
        }
    }
    __syncthreads();
    // fused q2c + bf16 pack + transposed store
    // j=q: 0:(a-d)->p0  1:(b+c)->p1  2:(a+d)->p10  3:(b-c)->p11
    int rowA = q & 1, rowB = 3 - (q & 1);
    float sgn = (q == 1 || q == 2) ? 1.f : -1.f;
    int p = (q < 2) ? q : q + 8;
    const float* qA = &qT[rowA][c][0];
    const float* qB = &qT[rowB][c][0];
    unsigned short* dst = sbT + ((p * 64 + c) * BT + b) * PPOS + wp * 28;
#pragma unroll
    for (int g = 0; g < 7; ++g) {
        float4 a4 = *(const float4*)(qA + g * 4);
        float4 b4 = *(const float4*)(qB + g * 4);
        float v0 = (a4.x + sgn * b4.x) * ISQ2;
        float v1 = (a4.y + sgn * b4.y) * ISQ2;
        float v2 = (a4.z + sgn * b4.z) * ISQ2;
        float v3 = (a4.w + sgn * b4.w) * ISQ2;
        uint2 pk;
        pk.x = (unsigned)f2bf(v0) | ((unsigned)f2bf(v1) << 16);
        pk.y = (unsigned)f2bf(v2) | ((unsigned)f2bf(v3) << 16);
        *(uint2*)(dst + g * 4) = pk;
    }
}

// ---- K2b: hi column filters -> subband planes 2..9 (bf16)
__global__ __launch_bounds__(256) void k_cols_hi(const float* __restrict__ hi,
                                                 unsigned short* __restrict__ sbT) {
    __shared__ float qT[2][4][64][29];  // 59.4 KB, pad 29
    int b = blockIdx.x / WH, wp = blockIdx.x % WH;
    int w0 = 2 * wp, tid = threadIdx.x;
    int q = tid >> 6, c = tid & 63;
    int rp = q >> 1, jc = q & 1;
    const float* colbase = hi + (b * HS) * WS * CH + (w0 + jc) * CH + c;
    {
        float W[19];
#pragma unroll
        for (int t = 0; t < 19; ++t) W[t] = colbase[symi(rp - 9 + t) * (WS * CH)];
#pragma unroll
        for (int i = 0; i < 28; ++i) {
            int h = 2 * i + rp;
            float vhl = 0.f, vhh = 0.f;
#pragma unroll
            for (int t = 0; t < 13; ++t) vhl += F_H0[t] * W[3 + t];
#pragma unroll
            for (int t = 0; t < 19; ++t) vhh += F_H1[t] * W[t];
            qT[0][q][c][i] = vhl;
            qT[1][q][c][i] = vhh;
#pragma unroll
            for (int t = 0; t < 17; ++t) W[t] = W[t + 2];
            W[17] = colbase[symi(h + 10) * (WS * CH)];
            W[18] = colbase[symi(h + 11) * (WS * CH)];
        }
    }
    __syncthreads();
    int rowA = q & 1, rowB = 3 - (q & 1);
    float sgn = (q == 1 || q == 2) ? 1.f : -1.f;
#pragma unroll
    for (int src = 0; src < 2; ++src) {
        // src0 (hl): planes 4,5,6,7 (s2,s3); src1 (hh): planes 2,3,8,9 (s1,s4)
        int p = (src == 0) ? (4 + q) : ((q < 2) ? (2 + q) : (6 + q));
        const float* qA = &qT[src][rowA][c][0];
        const float* qB = &qT[src][rowB][c][0];
        unsigned short* dst = sbT + ((p * 64 + c) * BT + b) * PPOS + wp * 28;
#pragma unroll
        for (int g = 0; g < 7; ++g) {
            float4 a4 = *(const float4*)(qA + g * 4);
            float4 b4 = *(const float4*)(qB + g * 4);
            float v0 = (a4.x + sgn * b4.x) * ISQ2;
            float v1 = (a4.y + sgn * b4.y) * ISQ2;
            float v2 = (a4.z + sgn * b4.z) * ISQ2;
            float v3 = (a4.w + sgn * b4.w) * ISQ2;
            uint2 pk;
            pk.x = (unsigned)f2bf(v0) | ((unsigned)f2bf(v1) << 16);
            pk.y = (unsigned)f2bf(v2) | ((unsigned)f2bf(v3) << 16);
            *(uint2*)(dst + g * 4) = pk;
        }
    }
}

// ---- K3: MFMA channel mixing + fused c2q. One wave handles both subbands of
// a c2q pair (weights are subband-independent) so the butterfly is register
// math; writes plain fp32 planes P[b][h][w][c]:
//   pr 0: (s0,s5)->P0 ; pr 1: (s2,s3)->P1 ; pr 2: (s1,s4)->P2
// l1 bounce buffers are wave-private -> no __syncthreads (DS in-order per wave).
__global__ __launch_bounds__(256) void k_mix(
    const unsigned short* __restrict__ sbT, const float* __restrict__ w1,
    const float* __restrict__ w2, const float* __restrict__ b1,
    const float* __restrict__ b2, float* __restrict__ P0,
    float* __restrict__ P1, float* __restrict__ P2) {
    __shared__ unsigned short l1a[4][16][36];
    __shared__ unsigned short l1b[4][16][36];
    int blk = blockIdx.x;
    int pr = blk / (BT * 7);
    int rem = blk % (BT * 7);
    int b = rem / 7;
    int chunk = rem % 7;
    int sa = (pr == 0) ? 0 : (pr == 1) ? 2 : 1;
    int sb = (pr == 0) ? 5 : (pr == 1) ? 3 : 4;
    float* Pd = (pr == 0) ? P0 : (pr == 1) ? P1 : P2;
    int tid = threadIdx.x;
    int lane = tid & 63;
    int wv = tid >> 6;
    int nb = __builtin_amdgcn_readfirstlane(wv);
    int quad = lane >> 4;
    int n = lane & 15;

    // weight fragments (B-operand): lane holds B[k=quad*8+j][n]
    short8 B1r, B1i, B2r, B2i;
#pragma unroll
    for (int j = 0; j < 8; ++j) {
        int kk = quad * 8 + j;
        int riw = kk >> 4, dd = kk & 15;
        float v1r = w1[nb * 256 + dd * 16 + n];
        float v1i = w1[1024 + nb * 256 + dd * 16 + n];
        float v2r = w2[nb * 256 + dd * 16 + n];
        float v2i = w2[1024 + nb * 256 + dd * 16 + n];
        B1r[j] = (short)f2bf(riw ? -v1i : v1r);
        B1i[j] = (short)f2bf(riw ? v1r : v1i);
        B2r[j] = (short)f2bf(riw ? -v2i : v2r);
        B2i[j] = (short)f2bf(riw ? v2r : v2i);
    }
    float bias1r = b1[nb * 16 + n], bias1i = b1[64 + nb * 16 + n];
    float bias2r = b2[nb * 16 + n], bias2i = b2[64 + nb * 16 + n];

    int pbase = chunk * 112;
    for (int t = 0; t < 7; ++t) {
        int pos0 = pbase + t * 16;
        // A1 frags for both subbands: lane holds A[m=n][k=quad*8+j]
        short8 A1a, A1b;
#pragma unroll
        for (int j = 0; j < 8; ++j) {
            int kk = quad * 8 + j;
            int rix = kk >> 4, dd = kk & 15;
            int cc = nb * 16 + dd;
            A1a[j] = (short)sbT[(((sa * 2 + rix) * 64 + cc) * BT + b) * PPOS + pos0 + n];
            A1b[j] = (short)sbT[(((sb * 2 + rix) * 64 + cc) * BT + b) * PPOS + pos0 + n];
        }
        f32x4 a1r = {bias1r, bias1r, bias1r, bias1r};
        f32x4 a1i = {bias1i, bias1i, bias1i, bias1i};
        f32x4 b1r_ = a1r, b1i_ = a1i;
        a1r = __builtin_amdgcn_mfma_f32_16x16x32_bf16(A1a, B1r, a1r, 0, 0, 0);
        a1i = __builtin_amdgcn_mfma_f32_16x16x32_bf16(A1a, B1i, a1i, 0, 0, 0);
        b1r_ = __builtin_amdgcn_mfma_f32_16x16x32_bf16(A1b, B1r, b1r_, 0, 0, 0);
        b1i_ = __builtin_amdgcn_mfma_f32_16x16x32_bf16(A1b, B1i, b1i_, 0, 0, 0);
#pragma unroll
        for (int r = 0; r < 4; ++r) {
            int pos = quad * 4 + r;
            l1a[wv][pos][n] = f2bf(fmaxf(a1r[r], 0.f));
            l1a[wv][pos][16 + n] = f2bf(fmaxf(a1i[r], 0.f));
            l1b[wv][pos][n] = f2bf(fmaxf(b1r_[r], 0.f));
            l1b[wv][pos][16 + n] = f2bf(fmaxf(b1i_[r], 0.f));
        }
        // wave-private bounce: compiler inserts lgkmcnt for the RAW dep
        union { short8 s8; uint2 u2[2]; } a2a, a2b;
        const unsigned short* rowpa = &l1a[wv][n][0];
        const unsigned short* rowpb = &l1b[wv][n][0];
        a2a.u2[0] = *(const uint2*)(rowpa + quad * 8);
        a2a.u2[1] = *(const uint2*)(rowpa + quad * 8 + 4);
        a2b.u2[0] = *(const uint2*)(rowpb + quad * 8);
        a2b.u2[1] = *(const uint2*)(rowpb + quad * 8 + 4);
        f32x4 aAr = {bias2r, bias2r, bias2r, bias2r};
        f32x4 aAi = {bias2i, bias2i, bias2i, bias2i};
        f32x4 aBr = aAr, aBi = aAi;
        aAr = __builtin_amdgcn_mfma_f32_16x16x32_bf16(a2a.s8, B2r, aAr, 0, 0, 0);
        aAi = __builtin_amdgcn_mfma_f32_16x16x32_bf16(a2a.s8, B2i, aAi, 0, 0, 0);
        aBr = __builtin_amdgcn_mfma_f32_16x16x32_bf16(a2b.s8, B2r, aBr, 0, 0, 0);
        aBi = __builtin_amdgcn_mfma_f32_16x16x32_bf16(a2b.s8, B2i, aBi, 0, 0, 0);
        // c2q butterfly in registers + quad store
#pragma unroll
        for (int r = 0; r < 4; ++r) {
            int pos_g = pos0 + quad * 4 + r;
            int wp = pos_g / 28, ii = pos_g - wp * 28;
            int o = ((b * HS + 2 * ii) * WS + 2 * wp) * CH + nb * 16 + n;
            Pd[o] = (aAr[r] + aBr[r]) * ISQ2;
            Pd[o + CH] = (aAi[r] + aBi[r]) * ISQ2;
            Pd[o + WS * CH] = (aAi[r] - aBi[r]) * ISQ2;
            Pd[o + WS * CH + CH] = (aBr[r] - aAr[r]) * ISQ2;
        }
    }
}

// ---- K4: inverse column filter pass: out = G0col(A) + G1col(B), plain planes
__global__ __launch_bounds__(256) void k_inv_cols2(const float* __restrict__ Ap,
                                                   const float* __restrict__ Bp,
                                                   float* __restrict__ outp) {
    int b = blockIdx.x / 14, wg = blockIdx.x % 14;
    int wl = threadIdx.x >> 6, c = threadIdx.x & 63;
    int w = wg * 4 + wl;
    int base = (b * HS) * WS * CH + w * CH + c;
    const int st = WS * CH;
    float A[19], B[13];
#pragma unroll
    for (int t = 0; t < 19; ++t) A[t] = Ap[base + symi(t - 9) * st];
#pragma unroll
    for (int t = 0; t < 13; ++t) B[t] = Bp[base + symi(t - 6) * st];
#pragma unroll
    for (int h = 0; h < 56; ++h) {
        float acc = 0.f;
#pragma unroll
        for (int t = 0; t < 19; ++t) acc += F_G0[t] * A[t];
#pragma unroll
        for (int t = 0; t < 13; ++t) acc += F_G1[t] * B[t];
        outp[base + h * st] = acc;
#pragma unroll
        for (int t = 0; t < 18; ++t) A[t] = A[t + 1];
#pragma unroll
        for (int t = 0; t < 12; ++t) B[t] = B[t + 1];
        A[18] = Ap[base + symi(h + 10) * st];
        B[12] = Bp[base + symi(h + 7) * st];
    }
}

// ---- K5: inverse row filters (sliding window, no LDS) -> out
__global__ __launch_bounds__(256) void k_inv_rows(const float* __restrict__ lo2,
                                                  const float* __restrict__ hi2,
                                                  float* __restrict__ out) {
    int b = blockIdx.x / HS, h = blockIdx.x % HS;
    int strip = threadIdx.x >> 6, c = threadIdx.x & 63;
    int base = (b * HS + h) * WS * CH + c;
    const float* rlo = lo2 + base;
    const float* rhi = hi2 + base;
    float* op = out + base;
    int w0s = strip * 14;
    float A[19], B[13];
#pragma unroll
    for (int t = 0; t < 19; ++t) A[t] = rlo[symi(w0s - 9 + t) * CH];
#pragma unroll
    for (int t = 0; t < 13; ++t) B[t] = rhi[symi(w0s - 6 + t) * CH];
#pragma unroll
    for (int k = 0; k < 14; ++k) {
        int w = w0s + k;
        float acc = 0.f;
#pragma unroll
        for (int t = 0; t < 19; ++t) acc += F_G0[t] * A[t];
#pragma unroll
        for (int t = 0; t < 13; ++t) acc += F_G1[t] * B[t];
        op[w * CH] = acc;
#pragma unroll
        for (int t = 0; t < 18; ++t) A[t] = A[t + 1];
#pragma unroll
        for (int t = 0; t < 12; ++t) B[t] = B[t + 1];
        A[18] = rlo[symi(w + 10) * CH];
        B[12] = rhi[symi(w + 7) * CH];
    }
}

extern "C" void kernel_launch(void* const* d_in, const int* in_sizes, int n_in,
                              void* d_out, int out_size, void* d_ws, size_t ws_size,
                              hipStream_t stream) {
    const float* x = (const float*)d_in[0];
    const float* w_ll = (const float*)d_in[1];
    const float* w1 = (const float*)d_in[2];
    const float* w2 = (const float*)d_in[3];
    const float* b1 = (const float*)d_in[4];
    const float* b2 = (const float*)d_in[5];
    float* out = (float*)d_out;

    // workspace (floats); A = one plane = 6,422,528 fl; peak end = 4A+9.63M
    // = 35.3M fl = 141 MB (< R1-proven 154 MB)
    const size_t A = (size_t)BT * HS * WS * CH;
    const size_t SB = (size_t)12 * 64 * BT * PPOS / 2;  // 9,633,792 fl (bf16 x2)
    float* wsf = (float*)d_ws;
    float* xl = wsf;                       // [0, A)  dead after inv_cols_lo
    float* hi2 = wsf;                      //   .. then reused for hi2
    unsigned short* sbT = (unsigned short*)(wsf + A);  // [A, A+SB) dead after mix
    float* lo2 = wsf + A;                  //   .. then reused for lo2
    float* P0 = wsf + A + SB;              // lo-in, then P0 = c2q(s0,s5)
    float* P1 = P0 + A;                    // hi-in, then P1 = c2q(s2,s3)
    float* P2 = P1 + A;                    // P2 = c2q(s1,s4)
    float* lo_in = P0;
    float* hi_in = P1;

    float* wllT = out;  // staged in d_out head (overwritten by k_inv_rows)

    k_wll_T<<<49, 256, 0, stream>>>(w_ll, wllT);
    k_fwd_rows<<<BT * HS, 256, 0, stream>>>(x, lo_in, hi_in);
    k_cols_lo<<<BT * WH, 256, 0, stream>>>(lo_in, wllT, xl, sbT);
    k_cols_hi<<<BT * WH, 256, 0, stream>>>(hi_in, sbT);
    k_mix<<<3 * BT * 7, 256, 0, stream>>>(sbT, w1, w2, b1, b2, P0, P1, P2);
    k_inv_cols2<<<BT * 14, 256, 0, stream>>>(xl, P0, lo2);   // lo2 (over sbT)
    k_inv_cols2<<<BT * 14, 256, 0, stream>>>(P1, P2, hi2);   // hi2 (over xl)
    k_inv_rows<<<BT * HS, 256, 0, stream>>>(lo2, hi2, out);
}